// Round 9
// baseline (3712.357 us; speedup 1.0000x reference)
//
#include <hip/hip_runtime.h>

typedef __attribute__((ext_vector_type(4))) int  i8x16;   // 16 packed int8 (4 VGPR MFMA operand)
typedef __attribute__((ext_vector_type(16))) int i32x16;  // 32x32 i32 accumulator
typedef __attribute__((ext_vector_type(8))) short bf16x8;
typedef __attribute__((ext_vector_type(8))) unsigned short ushort8;
typedef __attribute__((ext_vector_type(4))) float f32x4;

__device__ __forceinline__ unsigned short f32_to_bf16(float f) {
    union { float f; unsigned int u; } v;
    v.f = f;
    unsigned int r = v.u + (0x7fffu + ((v.u >> 16) & 1u));
    return (unsigned short)(r >> 16);
}

__device__ __forceinline__ void gload_lds16(const void* g, void* l) {
    __builtin_amdgcn_global_load_lds(
        (const __attribute__((address_space(1))) unsigned int*)g,
        (__attribute__((address_space(3))) unsigned int*)l, 16, 0, 0);
}

// ---------------- x -> int8 per-row symmetric quantization ----------------
__global__ __launch_bounds__(256) void quantx_kernel(const float* __restrict__ x,
                                                     char* __restrict__ xq,
                                                     float* __restrict__ rs, int K) {
    const int row = blockIdx.x;
    const float4* xr = (const float4*)(x + (size_t)row * K);
    const int K4 = K >> 2;
    const int t = threadIdx.x;
    float am = 0.f;
    for (int i = t; i < K4; i += 256) {
        float4 v = xr[i];
        am = fmaxf(am, fmaxf(fmaxf(fabsf(v.x), fabsf(v.y)),
                             fmaxf(fabsf(v.z), fabsf(v.w))));
    }
    for (int off = 32; off; off >>= 1) am = fmaxf(am, __shfl_xor(am, off));
    __shared__ float ws[4];
    if ((t & 63) == 0) ws[t >> 6] = am;
    __syncthreads();
    am = fmaxf(fmaxf(ws[0], ws[1]), fmaxf(ws[2], ws[3]));
    const float inv = am > 0.f ? 127.f / am : 0.f;
    if (t == 0) rs[row] = am > 0.f ? am / 127.f : 0.f;
    int* dst = (int*)(xq + (size_t)row * K);
    for (int i = t; i < K4; i += 256) {
        float4 v = xr[i];
        int a = (int)rintf(v.x * inv), b = (int)rintf(v.y * inv);
        int c = (int)rintf(v.z * inv), d = (int)rintf(v.w * inv);
        dst[i] = (a & 255) | ((b & 255) << 8) | ((c & 255) << 16) | (d << 24);
    }
}

// ---------------- qweight int32 -> int8 ----------------
__global__ void convq_kernel(const int* __restrict__ q, char* __restrict__ qb, long n16) {
    long i = (long)blockIdx.x * blockDim.x + threadIdx.x;
    const long stride = (long)gridDim.x * blockDim.x;
    for (; i < n16; i += stride) {
        const int4* p = (const int4*)(q + i * 16);
        int4 a = p[0], b = p[1], c = p[2], d = p[3];
        int4 r;
        r.x = (a.x & 255) | ((a.y & 255) << 8) | ((a.z & 255) << 16) | (a.w << 24);
        r.y = (b.x & 255) | ((b.y & 255) << 8) | ((b.z & 255) << 16) | (b.w << 24);
        r.z = (c.x & 255) | ((c.y & 255) << 8) | ((c.z & 255) << 16) | (c.w << 24);
        r.w = (d.x & 255) | ((d.y & 255) << 8) | ((d.z & 255) << 16) | (d.w << 24);
        ((int4*)qb)[i] = r;
    }
}

// ---------------- 256x256 int8 GEMM (mfma_i32_32x32x32_i8, BK=128) ----------
// C[m,n] = sum_k xq[m,k]*qb[n,k] (i32 exact); out = C * rs[m]*scale[n] + bias[n]
// 512 thr, 8 waves (2x4), per-wave 128x64 = 4mf x 2nf 32x32 frags, 4 ks.
// LDS 128KB: A bufs 2x32KB @0/32768, B bufs 2x32KB @65536/98304.
// Tile = 256 rows x 128 i8 (128B rows, 8x16B chunks; chunk s at slot s^(r&7)).
// Operand layout: lane l holds 16 contiguous k-bytes at row l&31, k-half l>>5
// (same contiguous-k pattern as the verified bf16 16x16x32 path).
// Sync (R7-proven skeleton): per tile P0{issue kh1 reads; LGKM(12); MFMA kh0}
// P1{LGKM(0); B1; stage t+2 -> cur; MFMA kh1; vmcnt(8); B2; read kh0(t+1)}.
__global__ __launch_bounds__(512, 2) void qgemm_i8_kernel(
    const char* __restrict__ A, const char* __restrict__ B,
    const float* __restrict__ rs, const float* __restrict__ scale,
    const float* __restrict__ bias, float* __restrict__ C, int M, int N, int K) {
    extern __shared__ char sm[];

    const int tid  = threadIdx.x;
    const int lane = tid & 63;
    const int w    = tid >> 6;
    const int wr   = w >> 2;                 // 0..1
    const int wc   = w & 3;                  // 0..3
    const int l31  = lane & 31;
    const int hi   = lane >> 5;              // 0..1
    const int swz7 = l31 & 7;

    // T1: bijective XCD swizzle (gridDim.x % 8 == 0 by construction)
    const int nwg = gridDim.x;
    const int bid = blockIdx.x;
    const int swz = (bid & 7) * (nwg >> 3) + (bid >> 3);
    const int nbx = N >> 8;
    const int m0  = (swz / nbx) << 8;
    const int n0  = (swz % nbx) << 8;

    // staging: chunk c = tid + 512j -> r = (tid>>3)+64j, s = tid&7 (swz same all j)
    const size_t binv0 = (size_t)(tid >> 3) * K +
                         (size_t)(((tid & 7) ^ ((tid >> 3) & 7)) << 4);
    const size_t bofs = (size_t)64 * K;      // 64 rows per round (bytes)
    const int bld = w << 10;

#define STAGE(LBASE, GSRC) do {                                     \
        gload_lds16((GSRC) + binv0,            (LBASE) + bld);      \
        gload_lds16((GSRC) + binv0 + bofs,     (LBASE) + bld + 8192); \
        gload_lds16((GSRC) + binv0 + 2*bofs,   (LBASE) + bld + 16384); \
        gload_lds16((GSRC) + binv0 + 3*bofs,   (LBASE) + bld + 24576); } while (0)

    // fragment byte bases (local rows * 128); + mf*4096 / + nf*4096
    const int aRow0 = (wr * 128 + l31) * 128;
    const int bRow0 = (wc * 64 + l31) * 128;

    const char* pA = A + (size_t)m0 * K;
    const char* pB = B + (size_t)n0 * K;
    const int NT = K >> 7;

    i32x16 acc[4][2];
#pragma unroll
    for (int mf = 0; mf < 4; ++mf)
#pragma unroll
        for (int nf = 0; nf < 2; ++nf)
#pragma unroll
            for (int r = 0; r < 16; ++r) acc[mf][nf][r] = 0;

#define RD_KH(AF, BF, BUFA, BUFB, KH) do {                                     \
    _Pragma("unroll") for (int mf = 0; mf < 4; ++mf)                           \
    _Pragma("unroll") for (int s = 0; s < 2; ++s)                              \
        (AF)[mf][s] = *(const i8x16*)((BUFA) + aRow0 + mf * 4096 +             \
            ((((KH) * 4 + s * 2 + hi) ^ swz7) << 4));                          \
    _Pragma("unroll") for (int nf = 0; nf < 2; ++nf)                           \
    _Pragma("unroll") for (int s = 0; s < 2; ++s)                              \
        (BF)[nf][s] = *(const i8x16*)((BUFB) + bRow0 + nf * 4096 +             \
            ((((KH) * 4 + s * 2 + hi) ^ swz7) << 4)); } while (0)
#define MFMA_KH(AF, BF) do {                                                   \
    _Pragma("unroll") for (int s = 0; s < 2; ++s)                              \
    _Pragma("unroll") for (int mf = 0; mf < 4; ++mf)                           \
    _Pragma("unroll") for (int nf = 0; nf < 2; ++nf)                           \
        acc[mf][nf] = __builtin_amdgcn_mfma_i32_32x32x32_i8(                   \
            (AF)[mf][s], (BF)[nf][s], acc[mf][nf], 0, 0, 0); } while (0)
#define LGKM(NM) do { asm volatile("s_waitcnt lgkmcnt(" #NM ")" ::: "memory"); \
                      __builtin_amdgcn_sched_barrier(0); } while (0)

    i8x16 aF0[4][2], aF1[4][2], bF0[2][2], bF1[2][2];

    // ---- prologue: stage tile0 + tile1 (16 gloads); read kh0(0) ----
    STAGE(sm + 0,     pA);                 // A(0)
    STAGE(sm + 65536, pB);                 // B(0)
    if (NT > 1) {
        STAGE(sm + 32768, pA + 128);       // A(1)
        STAGE(sm + 98304, pB + 128);       // B(1)
        asm volatile("s_waitcnt vmcnt(8)" ::: "memory");
    } else {
        asm volatile("s_waitcnt vmcnt(0)" ::: "memory");
    }
    __builtin_amdgcn_s_barrier();
    __builtin_amdgcn_sched_barrier(0);
    RD_KH(aF0, bF0, sm, sm + 65536, 0);    // 12 ds_read_b128

    for (int t = 0; t < NT; ++t) {
        char* Ac = sm + (t & 1) * 32768;
        char* Bc = sm + 65536 + (t & 1) * 32768;
        char* An = sm + ((t & 1) ^ 1) * 32768;
        char* Bn = sm + 65536 + ((t & 1) ^ 1) * 32768;

        // ---- P0: issue kh1 reads; wait kh0 (12 oldest); MFMA kh0 ----
        RD_KH(aF1, bF1, Ac, Bc, 1);        // +12 -> 24 outstanding
        LGKM(12);
        __builtin_amdgcn_s_setprio(1);
        MFMA_KH(aF0, bF0);
        __builtin_amdgcn_s_setprio(0);

        // ---- P1 ----
        LGKM(0);                           // all my reads of cur done
        if (t + 1 < NT) {
            __builtin_amdgcn_s_barrier();  // B1: cur free for re-staging
            if (t + 2 < NT) {
                STAGE(Ac, pA + (size_t)(t + 2) * 128);
                STAGE(Bc, pB + (size_t)(t + 2) * 128);
            }
            __builtin_amdgcn_s_setprio(1);
            MFMA_KH(aF1, bF1);
            __builtin_amdgcn_s_setprio(0);
            if (t + 2 < NT) asm volatile("s_waitcnt vmcnt(8)" ::: "memory");
            else            asm volatile("s_waitcnt vmcnt(0)" ::: "memory");
            __builtin_amdgcn_s_barrier();  // B2: publish tile t+1
            __builtin_amdgcn_sched_barrier(0);
            RD_KH(aF0, bF0, An, Bn, 0);    // kh0(t+1)
        } else {
            __builtin_amdgcn_s_setprio(1);
            MFMA_KH(aF1, bF1);
            __builtin_amdgcn_s_setprio(0);
        }
    }

    // ---- epilogue: out = acc * (rs[row]*scale[col]) + bias[col] ----
    // C/D layout (m74/m101, i8-verified m121-128): col=lane&31,
    // row=(reg&3)+8*(reg>>2)+4*(lane>>5)
#pragma unroll
    for (int mf = 0; mf < 4; ++mf) {
        const int rbase = m0 + wr * 128 + mf * 32 + 4 * hi;
        float rsv[16];
#pragma unroll
        for (int g = 0; g < 4; ++g)
#pragma unroll
            for (int j = 0; j < 4; ++j) rsv[g * 4 + j] = rs[rbase + 8 * g + j];
#pragma unroll
        for (int nf = 0; nf < 2; ++nf) {
            const int col = n0 + wc * 64 + nf * 32 + l31;
            const float sc = scale[col];
            const float bs = bias[col];
#pragma unroll
            for (int reg = 0; reg < 16; ++reg) {
                const int row = rbase + 8 * (reg >> 2) + (reg & 3);
                C[(size_t)row * N + col] =
                    (float)acc[mf][nf][reg] * (rsv[reg] * sc) + bs;
            }
        }
    }
#undef STAGE
#undef RD_KH
#undef MFMA_KH
#undef LGKM
}

// ---------------- fallback (shape mismatch): 2-phase bf16, on-the-fly ----
__global__ __launch_bounds__(256) void qgemm_fb_kernel(
    const float* __restrict__ Af, const int* __restrict__ Bi,
    const float* __restrict__ scale, const float* __restrict__ bias,
    float* __restrict__ C, int M, int N, int K) {
    constexpr int BK = 64;
    __shared__ unsigned short lA[128 * BK];
    __shared__ unsigned short lB[128 * BK];
    const int t = threadIdx.x, lane = t & 63, w = t >> 6;
    const int wr = w >> 1, wc = w & 1;
    const int m0 = blockIdx.y * 128, n0 = blockIdx.x * 128;
    const int l15 = lane & 15, l4 = lane >> 4;
    f32x4 acc[4][4];
#pragma unroll
    for (int m = 0; m < 4; ++m)
#pragma unroll
        for (int n = 0; n < 4; ++n) acc[m][n] = (f32x4){0.f, 0.f, 0.f, 0.f};
    for (int k0 = 0; k0 < K; k0 += BK) {
        __syncthreads();
#pragma unroll
        for (int i = 0; i < 4; ++i) {
            const int off = i * 4096 + w * 1024 + lane * 16;
            const int row = off >> 7;
            const int col = (off & 127) >> 1;
            const float* pa = Af + (size_t)(m0 + row) * K + k0 + col;
            float4 a0 = *(const float4*)pa;
            float4 a1 = *(const float4*)(pa + 4);
            ushort8 va;
            va[0] = f32_to_bf16(a0.x); va[1] = f32_to_bf16(a0.y);
            va[2] = f32_to_bf16(a0.z); va[3] = f32_to_bf16(a0.w);
            va[4] = f32_to_bf16(a1.x); va[5] = f32_to_bf16(a1.y);
            va[6] = f32_to_bf16(a1.z); va[7] = f32_to_bf16(a1.w);
            *(ushort8*)((char*)lA + off) = va;
            const int* pb = Bi + (size_t)(n0 + row) * K + k0 + col;
            int4 b0 = *(const int4*)pb;
            int4 b1 = *(const int4*)(pb + 4);
            ushort8 vb;
            vb[0] = f32_to_bf16((float)b0.x); vb[1] = f32_to_bf16((float)b0.y);
            vb[2] = f32_to_bf16((float)b0.z); vb[3] = f32_to_bf16((float)b0.w);
            vb[4] = f32_to_bf16((float)b1.x); vb[5] = f32_to_bf16((float)b1.y);
            vb[6] = f32_to_bf16((float)b1.z); vb[7] = f32_to_bf16((float)b1.w);
            *(ushort8*)((char*)lB + off) = vb;
        }
        __syncthreads();
#pragma unroll
        for (int kk = 0; kk < BK; kk += 32) {
            bf16x8 af[4], bfr[4];
#pragma unroll
            for (int m = 0; m < 4; ++m)
                af[m] = *(const bf16x8*)&lA[(wr * 64 + m * 16 + l15) * BK + kk + l4 * 8];
#pragma unroll
            for (int n = 0; n < 4; ++n)
                bfr[n] = *(const bf16x8*)&lB[(wc * 64 + n * 16 + l15) * BK + kk + l4 * 8];
#pragma unroll
            for (int m = 0; m < 4; ++m)
#pragma unroll
                for (int n = 0; n < 4; ++n)
                    acc[m][n] = __builtin_amdgcn_mfma_f32_16x16x32_bf16(
                        af[m], bfr[n], acc[m][n], 0, 0, 0);
        }
    }
#pragma unroll
    for (int n = 0; n < 4; ++n) {
        const int col = n0 + wc * 64 + n * 16 + l15;
        const float sc = scale[col], bs = bias[col];
#pragma unroll
        for (int m = 0; m < 4; ++m) {
            const int row0 = m0 + wr * 64 + m * 16 + l4 * 4;
#pragma unroll
            for (int j = 0; j < 4; ++j)
                C[(size_t)(row0 + j) * N + col] = fmaf(acc[m][n][j], sc, bs);
        }
    }
}

extern "C" void kernel_launch(void* const* d_in, const int* in_sizes, int n_in,
                              void* d_out, int out_size, void* d_ws, size_t ws_size,
                              hipStream_t stream) {
    const float* x     = (const float*)d_in[0];
    const int*   q     = (const int*)d_in[1];
    const float* scale = (const float*)d_in[2];
    const float* bias  = (const float*)d_in[3];
    float*       out   = (float*)d_out;

    const int K = in_sizes[2];
    const int N = in_sizes[1] / K;
    const int M = in_sizes[0] / K;

    const size_t xq_b = (size_t)M * K;
    const size_t qb_b = (size_t)N * K;
    const size_t need = xq_b + qb_b + (size_t)M * 4;
    const int nwg = (M / 256) * (N / 256);

    if (ws_size >= need && (M % 256) == 0 && (N % 256) == 0 &&
        (K % 128) == 0 && K >= 256 && (K % 4) == 0 && (nwg % 8) == 0) {
        char*  xq = (char*)d_ws;
        char*  qb = xq + xq_b;
        float* rs = (float*)(qb + qb_b);
        quantx_kernel<<<M, 256, 0, stream>>>(x, xq, rs, K);
        convq_kernel<<<2048, 256, 0, stream>>>(q, qb, (long)(qb_b / 16));
        qgemm_i8_kernel<<<nwg, 512, 131072, stream>>>(xq, qb, rs, scale, bias,
                                                      out, M, N, K);
    } else {
        dim3 grid(N / 128, M / 128);
        qgemm_fb_kernel<<<grid, 256, 0, stream>>>(x, q, scale, bias, out, M, N, K);
    }
}

// Round 10
// 413.327 us; speedup vs baseline: 8.9816x; 8.9816x over previous
//
#include <hip/hip_runtime.h>

typedef __attribute__((ext_vector_type(4))) int  i8x16;   // 16 packed int8 (4 VGPR MFMA operand)
typedef __attribute__((ext_vector_type(16))) int i32x16;  // 32x32 i32 accumulator
typedef __attribute__((ext_vector_type(8))) short bf16x8;
typedef __attribute__((ext_vector_type(8))) unsigned short ushort8;
typedef __attribute__((ext_vector_type(4))) float f32x4;

__device__ __forceinline__ unsigned short f32_to_bf16(float f) {
    union { float f; unsigned int u; } v;
    v.f = f;
    unsigned int r = v.u + (0x7fffu + ((v.u >> 16) & 1u));
    return (unsigned short)(r >> 16);
}

__device__ __forceinline__ void gload_lds16(const void* g, void* l) {
    __builtin_amdgcn_global_load_lds(
        (const __attribute__((address_space(1))) unsigned int*)g,
        (__attribute__((address_space(3))) unsigned int*)l, 16, 0, 0);
}

// ---------------- x -> int8 per-row symmetric quantization ----------------
__global__ __launch_bounds__(256) void quantx_kernel(const float* __restrict__ x,
                                                     char* __restrict__ xq,
                                                     float* __restrict__ rs, int K) {
    const int row = blockIdx.x;
    const float4* xr = (const float4*)(x + (size_t)row * K);
    const int K4 = K >> 2;
    const int t = threadIdx.x;
    float am = 0.f;
    for (int i = t; i < K4; i += 256) {
        float4 v = xr[i];
        am = fmaxf(am, fmaxf(fmaxf(fabsf(v.x), fabsf(v.y)),
                             fmaxf(fabsf(v.z), fabsf(v.w))));
    }
    for (int off = 32; off; off >>= 1) am = fmaxf(am, __shfl_xor(am, off));
    __shared__ float ws[4];
    if ((t & 63) == 0) ws[t >> 6] = am;
    __syncthreads();
    am = fmaxf(fmaxf(ws[0], ws[1]), fmaxf(ws[2], ws[3]));
    const float inv = am > 0.f ? 127.f / am : 0.f;
    if (t == 0) rs[row] = am > 0.f ? am / 127.f : 0.f;
    int* dst = (int*)(xq + (size_t)row * K);
    for (int i = t; i < K4; i += 256) {
        float4 v = xr[i];
        int a = (int)rintf(v.x * inv), b = (int)rintf(v.y * inv);
        int c = (int)rintf(v.z * inv), d = (int)rintf(v.w * inv);
        dst[i] = (a & 255) | ((b & 255) << 8) | ((c & 255) << 16) | (d << 24);
    }
}

// ---------------- qweight int32 -> int8 ----------------
__global__ void convq_kernel(const int* __restrict__ q, char* __restrict__ qb, long n16) {
    long i = (long)blockIdx.x * blockDim.x + threadIdx.x;
    const long stride = (long)gridDim.x * blockDim.x;
    for (; i < n16; i += stride) {
        const int4* p = (const int4*)(q + i * 16);
        int4 a = p[0], b = p[1], c = p[2], d = p[3];
        int4 r;
        r.x = (a.x & 255) | ((a.y & 255) << 8) | ((a.z & 255) << 16) | (a.w << 24);
        r.y = (b.x & 255) | ((b.y & 255) << 8) | ((b.z & 255) << 16) | (b.w << 24);
        r.z = (c.x & 255) | ((c.y & 255) << 8) | ((c.z & 255) << 16) | (c.w << 24);
        r.w = (d.x & 255) | ((d.y & 255) << 8) | ((d.z & 255) << 16) | (d.w << 24);
        ((int4*)qb)[i] = r;
    }
}

// ---------------- 256x256 int8 GEMM (mfma_i32_32x32x32_i8, BK=128) ----------
// C[m,n] = sum_k xq[m,k]*qb[n,k] (i32 exact); out = C * rs[m]*scale[n] + bias[n]
// 512 thr, 8 waves (2x4), per-wave 128x64 = 4mf x 2nf 32x32 frags.
// LDS 128KB: A bufs 2x32KB @0/32768, B bufs 2x32KB @65536/98304.
// Tile = 256 rows x 128 i8 (128B rows, 8x16B chunks; chunk s at slot s^(r&7)).
// Operand: lane l holds 16 contiguous k-bytes at row l&31, k-half l>>5.
// R10 vs R9: SINGLE fragment set (aF/bF reused across kh) -> live regs
// ~200 < 256 unified budget (R9's dual sets spilled: 10GB scratch writes).
// Sync: R7-proven 2-barrier skeleton; LGKM(0) before each MFMA cluster;
// cross-wave overlap (2 waves/SIMD) hides the exposed LDS reads.
__global__ __launch_bounds__(512, 2) void qgemm_i8_kernel(
    const char* __restrict__ A, const char* __restrict__ B,
    const float* __restrict__ rs, const float* __restrict__ scale,
    const float* __restrict__ bias, float* __restrict__ C, int M, int N, int K) {
    extern __shared__ char sm[];

    const int tid  = threadIdx.x;
    const int lane = tid & 63;
    const int w    = tid >> 6;
    const int wr   = w >> 2;                 // 0..1
    const int wc   = w & 3;                  // 0..3
    const int l31  = lane & 31;
    const int hi   = lane >> 5;              // 0..1
    const int swz7 = l31 & 7;

    // T1: bijective XCD swizzle (gridDim.x % 8 == 0 by construction)
    const int nwg = gridDim.x;
    const int bid = blockIdx.x;
    const int swz = (bid & 7) * (nwg >> 3) + (bid >> 3);
    const int nbx = N >> 8;
    const int m0  = (swz / nbx) << 8;
    const int n0  = (swz % nbx) << 8;

    // staging: chunk c = tid + 512j -> r = (tid>>3)+64j, s = tid&7
    const size_t binv0 = (size_t)(tid >> 3) * K +
                         (size_t)(((tid & 7) ^ ((tid >> 3) & 7)) << 4);
    const size_t bofs = (size_t)64 * K;      // 64 rows per round (bytes)
    const int bld = w << 10;

#define STAGE(LBASE, GSRC) do {                                       \
        gload_lds16((GSRC) + binv0,          (LBASE) + bld);          \
        gload_lds16((GSRC) + binv0 + bofs,   (LBASE) + bld + 8192);   \
        gload_lds16((GSRC) + binv0 + 2*bofs, (LBASE) + bld + 16384);  \
        gload_lds16((GSRC) + binv0 + 3*bofs, (LBASE) + bld + 24576); } while (0)

    // fragment byte bases (local rows * 128B); + mf*4096 / + nf*4096
    const int aRow0 = (wr * 128 + l31) * 128;
    const int bRow0 = (wc * 64 + l31) * 128;

    const char* pA = A + (size_t)m0 * K;
    const char* pB = B + (size_t)n0 * K;
    const int NT = K >> 7;

    i32x16 acc[4][2];
#pragma unroll
    for (int mf = 0; mf < 4; ++mf)
#pragma unroll
        for (int nf = 0; nf < 2; ++nf)
#pragma unroll
            for (int r = 0; r < 16; ++r) acc[mf][nf][r] = 0;

#define RD_KH(BUFA, BUFB, KH) do {                                             \
    _Pragma("unroll") for (int mf = 0; mf < 4; ++mf)                           \
    _Pragma("unroll") for (int s = 0; s < 2; ++s)                              \
        aF[mf][s] = *(const i8x16*)((BUFA) + aRow0 + mf * 4096 +               \
            ((((KH) * 4 + s * 2 + hi) ^ swz7) << 4));                          \
    _Pragma("unroll") for (int nf = 0; nf < 2; ++nf)                           \
    _Pragma("unroll") for (int s = 0; s < 2; ++s)                              \
        bF[nf][s] = *(const i8x16*)((BUFB) + bRow0 + nf * 4096 +               \
            ((((KH) * 4 + s * 2 + hi) ^ swz7) << 4)); } while (0)
#define MFMA_KH() do {                                                         \
    _Pragma("unroll") for (int s = 0; s < 2; ++s)                              \
    _Pragma("unroll") for (int mf = 0; mf < 4; ++mf)                           \
    _Pragma("unroll") for (int nf = 0; nf < 2; ++nf)                           \
        acc[mf][nf] = __builtin_amdgcn_mfma_i32_32x32x32_i8(                   \
            aF[mf][s], bF[nf][s], acc[mf][nf], 0, 0, 0); } while (0)
#define LGKM0() do { asm volatile("s_waitcnt lgkmcnt(0)" ::: "memory");        \
                     __builtin_amdgcn_sched_barrier(0); } while (0)

    i8x16 aF[4][2], bF[2][2];

    // ---- prologue: stage tile0 + tile1 (16 gloads) ----
    STAGE(sm + 0,     pA);                 // A(0)
    STAGE(sm + 65536, pB);                 // B(0)
    if (NT > 1) {
        STAGE(sm + 32768, pA + 128);       // A(1)
        STAGE(sm + 98304, pB + 128);       // B(1)
        asm volatile("s_waitcnt vmcnt(8)" ::: "memory");
    } else {
        asm volatile("s_waitcnt vmcnt(0)" ::: "memory");
    }
    __builtin_amdgcn_s_barrier();

    for (int t = 0; t < NT; ++t) {
        char* Ac = sm + (t & 1) * 32768;
        char* Bc = sm + 65536 + (t & 1) * 32768;

        // kh0
        RD_KH(Ac, Bc, 0);
        LGKM0();
        __builtin_amdgcn_s_setprio(1);
        MFMA_KH();
        __builtin_amdgcn_s_setprio(0);

        // kh1
        RD_KH(Ac, Bc, 1);
        LGKM0();
        __builtin_amdgcn_s_setprio(1);
        MFMA_KH();
        __builtin_amdgcn_s_setprio(0);

        if (t + 1 < NT) {
            __builtin_amdgcn_s_barrier();      // B1: all waves done reading cur
            if (t + 2 < NT) {
                STAGE(Ac, pA + (size_t)(t + 2) * 128);
                STAGE(Bc, pB + (size_t)(t + 2) * 128);
                asm volatile("s_waitcnt vmcnt(8)" ::: "memory");  // t+1 landed
            } else {
                asm volatile("s_waitcnt vmcnt(0)" ::: "memory");
            }
            __builtin_amdgcn_s_barrier();      // B2: publish tile t+1
        }
    }

    // ---- epilogue: out = acc * (rs[row]*scale[col]) + bias[col] ----
    // C/D layout (m74/m101, i8-verified m121-128): col=lane&31,
    // row=(reg&3)+8*(reg>>2)+4*(lane>>5)
#pragma unroll
    for (int mf = 0; mf < 4; ++mf) {
        const int rbase = m0 + wr * 128 + mf * 32 + 4 * hi;
#pragma unroll
        for (int nf = 0; nf < 2; ++nf) {
            const int col = n0 + wc * 64 + nf * 32 + l31;
            const float sc = scale[col];
            const float bs = bias[col];
#pragma unroll
            for (int reg = 0; reg < 16; ++reg) {
                const int row = rbase + 8 * (reg >> 2) + (reg & 3);
                C[(size_t)row * N + col] =
                    (float)acc[mf][nf][reg] * (rs[row] * sc) + bs;
            }
        }
    }
#undef STAGE
#undef RD_KH
#undef MFMA_KH
#undef LGKM0
}

// ---------------- fallback (shape mismatch): 2-phase bf16, on-the-fly ----
__global__ __launch_bounds__(256) void qgemm_fb_kernel(
    const float* __restrict__ Af, const int* __restrict__ Bi,
    const float* __restrict__ scale, const float* __restrict__ bias,
    float* __restrict__ C, int M, int N, int K) {
    constexpr int BK = 64;
    __shared__ unsigned short lA[128 * BK];
    __shared__ unsigned short lB[128 * BK];
    const int t = threadIdx.x, lane = t & 63, w = t >> 6;
    const int wr = w >> 1, wc = w & 1;
    const int m0 = blockIdx.y * 128, n0 = blockIdx.x * 128;
    const int l15 = lane & 15, l4 = lane >> 4;
    f32x4 acc[4][4];
#pragma unroll
    for (int m = 0; m < 4; ++m)
#pragma unroll
        for (int n = 0; n < 4; ++n) acc[m][n] = (f32x4){0.f, 0.f, 0.f, 0.f};
    for (int k0 = 0; k0 < K; k0 += BK) {
        __syncthreads();
#pragma unroll
        for (int i = 0; i < 4; ++i) {
            const int off = i * 4096 + w * 1024 + lane * 16;
            const int row = off >> 7;
            const int col = (off & 127) >> 1;
            const float* pa = Af + (size_t)(m0 + row) * K + k0 + col;
            float4 a0 = *(const float4*)pa;
            float4 a1 = *(const float4*)(pa + 4);
            ushort8 va;
            va[0] = f32_to_bf16(a0.x); va[1] = f32_to_bf16(a0.y);
            va[2] = f32_to_bf16(a0.z); va[3] = f32_to_bf16(a0.w);
            va[4] = f32_to_bf16(a1.x); va[5] = f32_to_bf16(a1.y);
            va[6] = f32_to_bf16(a1.z); va[7] = f32_to_bf16(a1.w);
            *(ushort8*)((char*)lA + off) = va;
            const int* pb = Bi + (size_t)(n0 + row) * K + k0 + col;
            int4 b0 = *(const int4*)pb;
            int4 b1 = *(const int4*)(pb + 4);
            ushort8 vb;
            vb[0] = f32_to_bf16((float)b0.x); vb[1] = f32_to_bf16((float)b0.y);
            vb[2] = f32_to_bf16((float)b0.z); vb[3] = f32_to_bf16((float)b0.w);
            vb[4] = f32_to_bf16((float)b1.x); vb[5] = f32_to_bf16((float)b1.y);
            vb[6] = f32_to_bf16((float)b1.z); vb[7] = f32_to_bf16((float)b1.w);
            *(ushort8*)((char*)lB + off) = vb;
        }
        __syncthreads();
#pragma unroll
        for (int kk = 0; kk < BK; kk += 32) {
            bf16x8 af[4], bfr[4];
#pragma unroll
            for (int m = 0; m < 4; ++m)
                af[m] = *(const bf16x8*)&lA[(wr * 64 + m * 16 + l15) * BK + kk + l4 * 8];
#pragma unroll
            for (int n = 0; n < 4; ++n)
                bfr[n] = *(const bf16x8*)&lB[(wc * 64 + n * 16 + l15) * BK + kk + l4 * 8];
#pragma unroll
            for (int m = 0; m < 4; ++m)
#pragma unroll
                for (int n = 0; n < 4; ++n)
                    acc[m][n] = __builtin_amdgcn_mfma_f32_16x16x32_bf16(
                        af[m], bfr[n], acc[m][n], 0, 0, 0);
        }
    }
#pragma unroll
    for (int n = 0; n < 4; ++n) {
        const int col = n0 + wc * 64 + n * 16 + l15;
        const float sc = scale[col], bs = bias[col];
#pragma unroll
        for (int m = 0; m < 4; ++m) {
            const int row0 = m0 + wr * 64 + m * 16 + l4 * 4;
#pragma unroll
            for (int j = 0; j < 4; ++j)
                C[(size_t)(row0 + j) * N + col] = fmaf(acc[m][n][j], sc, bs);
        }
    }
}

extern "C" void kernel_launch(void* const* d_in, const int* in_sizes, int n_in,
                              void* d_out, int out_size, void* d_ws, size_t ws_size,
                              hipStream_t stream) {
    const float* x     = (const float*)d_in[0];
    const int*   q     = (const int*)d_in[1];
    const float* scale = (const float*)d_in[2];
    const float* bias  = (const float*)d_in[3];
    float*       out   = (float*)d_out;

    const int K = in_sizes[2];
    const int N = in_sizes[1] / K;
    const int M = in_sizes[0] / K;

    const size_t xq_b = (size_t)M * K;
    const size_t qb_b = (size_t)N * K;
    const size_t need = xq_b + qb_b + (size_t)M * 4;
    const int nwg = (M / 256) * (N / 256);

    if (ws_size >= need && (M % 256) == 0 && (N % 256) == 0 &&
        (K % 128) == 0 && K >= 256 && (nwg % 8) == 0) {
        char*  xq = (char*)d_ws;
        char*  qb = xq + xq_b;
        float* rs = (float*)(qb + qb_b);
        quantx_kernel<<<M, 256, 0, stream>>>(x, xq, rs, K);
        convq_kernel<<<2048, 256, 0, stream>>>(q, qb, (long)(qb_b / 16));
        qgemm_i8_kernel<<<nwg, 512, 131072, stream>>>(xq, qb, rs, scale, bias,
                                                      out, M, N, K);
    } else {
        dim3 grid(N / 128, M / 128);
        qgemm_fb_kernel<<<grid, 256, 0, stream>>>(x, q, scale, bias, out, M, N, K);
    }
}

// Round 11
// 368.255 us; speedup vs baseline: 10.0810x; 1.1224x over previous
//
#include <hip/hip_runtime.h>

typedef __attribute__((ext_vector_type(4))) int  i8x16;   // 16 packed int8 (4 VGPR MFMA operand)
typedef __attribute__((ext_vector_type(4))) int  i32x4;   // 16x16 i32 accumulator
typedef __attribute__((ext_vector_type(8))) short bf16x8;
typedef __attribute__((ext_vector_type(8))) unsigned short ushort8;
typedef __attribute__((ext_vector_type(4))) float f32x4;

__device__ __forceinline__ unsigned short f32_to_bf16(float f) {
    union { float f; unsigned int u; } v;
    v.f = f;
    unsigned int r = v.u + (0x7fffu + ((v.u >> 16) & 1u));
    return (unsigned short)(r >> 16);
}

__device__ __forceinline__ void gload_lds16(const void* g, void* l) {
    __builtin_amdgcn_global_load_lds(
        (const __attribute__((address_space(1))) unsigned int*)g,
        (__attribute__((address_space(3))) unsigned int*)l, 16, 0, 0);
}

// ---------------- x -> int8 per-row symmetric quantization ----------------
__global__ __launch_bounds__(256) void quantx_kernel(const float* __restrict__ x,
                                                     char* __restrict__ xq,
                                                     float* __restrict__ rs, int K) {
    const int row = blockIdx.x;
    const float4* xr = (const float4*)(x + (size_t)row * K);
    const int K4 = K >> 2;
    const int t = threadIdx.x;
    float am = 0.f;
    for (int i = t; i < K4; i += 256) {
        float4 v = xr[i];
        am = fmaxf(am, fmaxf(fmaxf(fabsf(v.x), fabsf(v.y)),
                             fmaxf(fabsf(v.z), fabsf(v.w))));
    }
    for (int off = 32; off; off >>= 1) am = fmaxf(am, __shfl_xor(am, off));
    __shared__ float ws[4];
    if ((t & 63) == 0) ws[t >> 6] = am;
    __syncthreads();
    am = fmaxf(fmaxf(ws[0], ws[1]), fmaxf(ws[2], ws[3]));
    const float inv = am > 0.f ? 127.f / am : 0.f;
    if (t == 0) rs[row] = am > 0.f ? am / 127.f : 0.f;
    int* dst = (int*)(xq + (size_t)row * K);
    for (int i = t; i < K4; i += 256) {
        float4 v = xr[i];
        int a = (int)rintf(v.x * inv), b = (int)rintf(v.y * inv);
        int c = (int)rintf(v.z * inv), d = (int)rintf(v.w * inv);
        dst[i] = (a & 255) | ((b & 255) << 8) | ((c & 255) << 16) | (d << 24);
    }
}

// ---------------- qweight int32 -> int8 ----------------
__global__ void convq_kernel(const int* __restrict__ q, char* __restrict__ qb, long n16) {
    long i = (long)blockIdx.x * blockDim.x + threadIdx.x;
    const long stride = (long)gridDim.x * blockDim.x;
    for (; i < n16; i += stride) {
        const int4* p = (const int4*)(q + i * 16);
        int4 a = p[0], b = p[1], c = p[2], d = p[3];
        int4 r;
        r.x = (a.x & 255) | ((a.y & 255) << 8) | ((a.z & 255) << 16) | (a.w << 24);
        r.y = (b.x & 255) | ((b.y & 255) << 8) | ((b.z & 255) << 16) | (b.w << 24);
        r.z = (c.x & 255) | ((c.y & 255) << 8) | ((c.z & 255) << 16) | (c.w << 24);
        r.w = (d.x & 255) | ((d.y & 255) << 8) | ((d.z & 255) << 16) | (d.w << 24);
        ((int4*)qb)[i] = r;
    }
}

// ---------------- 256x256 i8 GEMM, 16x16x64 MFMA, R7 2-barrier schedule -----
// C[m,n] = sum_k xq[m,k]*qb[n,k] (i32 exact); out = C * rs[m]*scale[n] + bias[n]
// Exact port of the PASSING R7 bf16 kernel (same LDS geometry: 128B rows,
// 8x16B slots, swizzle slot s^(r&7), 2-way-conflict-free reads measured 0):
// bf16x8 -> i8x16, f32x4 -> i32x4, K-tile = 128 BYTES (NT = K/128),
// mfma_f32_16x16x32_bf16 -> mfma_i32_16x16x64_i8 (lane: row l&15,
// 16 contiguous k-bytes at 16*(l>>4); kk0 = slots 0-3, kk1 = slots 4-7).
// Sync/staging schedule identical to R7 (race-audited, PASSED).
__global__ __launch_bounds__(512, 2) void qgemm_i8_kernel(
    const char* __restrict__ A, const char* __restrict__ B,
    const float* __restrict__ rs, const float* __restrict__ scale,
    const float* __restrict__ bias, float* __restrict__ C, int M, int N, int K) {
    extern __shared__ char sm[];

    const int tid  = threadIdx.x;
    const int lane = tid & 63;
    const int w    = tid >> 6;
    const int wr   = w >> 2;                  // 0..1
    const int wc   = w & 3;                   // 0..3
    const int l15  = lane & 15;
    const int l4   = lane >> 4;
    const int r7   = l15 & 7;

    // T1: bijective XCD swizzle (gridDim.x % 8 == 0 by construction)
    const int nwg = gridDim.x;
    const int bid = blockIdx.x;
    const int swz = (bid & 7) * (nwg >> 3) + (bid >> 3);
    const int nbx = N >> 8;
    const int m0  = (swz / nbx) << 8;
    const int n0  = (swz % nbx) << 8;

    // staging: chunk c -> r=c>>3, s=(c&7)^(r&7); src byte = r*K + s*16
    const int c0 = tid, c1 = tid + 512;
    const size_t inv0 = (size_t)(c0 >> 3) * K + (size_t)((((c0 & 7) ^ ((c0 >> 3) & 7))) << 4);
    const size_t inv1 = (size_t)(c1 >> 3) * K + (size_t)((((c1 & 7) ^ ((c1 >> 3) & 7))) << 4);
    const int ldst0 = w << 10;
    const int ldst1 = (w << 10) + 8192;

#define STAGE(ldsHalf, gsrc) do {                         \
        gload_lds16((gsrc) + inv0, (ldsHalf) + ldst0);    \
        gload_lds16((gsrc) + inv1, (ldsHalf) + ldst1); } while (0)

    // fragment read offsets (bytes) -- identical to R7
    const int aRow0 = (wr * 128 + l15) * 128;  // + m*2048
    const int bRow0 = (wc * 64 + l15) * 128;   // + n*2048
    const int sl0   = ((0 + l4) ^ r7) << 4;    // kk=0: k-bytes 0-63
    const int sl1   = ((4 + l4) ^ r7) << 4;    // kk=1: k-bytes 64-127

    const char* pA = A + (size_t)m0 * K;
    const char* pB = B + (size_t)n0 * K;
    const size_t hK = (size_t)128 * K;
    const int NT = K >> 7;                     // 128 bytes of K per tile

    i32x4 acc[8][4];
#pragma unroll
    for (int m = 0; m < 8; ++m)
#pragma unroll
        for (int n = 0; n < 4; ++n) acc[m][n] = (i32x4){0, 0, 0, 0};

#define RD_A(DST, BUF, MB)                                                     \
    _Pragma("unroll") for (int m = 0; m < 4; ++m) {                            \
        (DST)[m][0] = *(const i8x16*)((BUF) + aRow0 + ((MB) + m) * 2048 + sl0); \
        (DST)[m][1] = *(const i8x16*)((BUF) + aRow0 + ((MB) + m) * 2048 + sl1); }
#define RD_B(DST, BUF, NB)                                                     \
    _Pragma("unroll") for (int n = 0; n < 2; ++n) {                            \
        (DST)[n][0] = *(const i8x16*)((BUF) + bRow0 + ((NB) + n) * 2048 + sl0); \
        (DST)[n][1] = *(const i8x16*)((BUF) + bRow0 + ((NB) + n) * 2048 + sl1); }
#define MFMA8(AF, BF, MB, NB)                                                  \
    _Pragma("unroll") for (int kk = 0; kk < 2; ++kk)                           \
    _Pragma("unroll") for (int m = 0; m < 4; ++m)                              \
    _Pragma("unroll") for (int n = 0; n < 2; ++n)                              \
        acc[(MB) + m][(NB) + n] = __builtin_amdgcn_mfma_i32_16x16x64_i8(       \
            (AF)[m][kk], (BF)[n][kk], acc[(MB) + m][(NB) + n], 0, 0, 0);
#define LGKM(N) do { asm volatile("s_waitcnt lgkmcnt(" #N ")" ::: "memory");   \
                     __builtin_amdgcn_sched_barrier(0); } while (0)

    i8x16 aF0[4][2], aF1[4][2], bF01[2][2], bF23[2][2];

    // ---- prologue: tile0 (4 halves) + B0/B1(tile1) [12 loads] ----
    STAGE(sm + 0,      pA);            // A0(0)
    STAGE(sm + 16384,  pA + hK);       // A1(0)
    STAGE(sm + 65536,  pB);            // B0(0)
    STAGE(sm + 81920,  pB + hK);       // B1(0)
    if (NT > 1) {
        STAGE(sm + 98304,  pB + 128);        // B0(1)
        STAGE(sm + 114688, pB + hK + 128);   // B1(1)
        asm volatile("s_waitcnt vmcnt(4)" ::: "memory");  // tile0 halves landed
    } else {
        asm volatile("s_waitcnt vmcnt(0)" ::: "memory");
    }
    __builtin_amdgcn_s_barrier();
    __builtin_amdgcn_sched_barrier(0);
    RD_A(aF0, sm, 0);                  // tile0 mh0   (8 reads)
    RD_B(bF01, sm + 65536, 0);         // tile0 n0,n1 (4 reads)
    RD_B(bF23, sm + 65536, 2);         // tile0 n2,n3 (4 reads)

    for (int t = 0; t < NT; ++t) {
        const int cur = t & 1;
        char* Ab = sm + cur * 32768;
        char* Bb = sm + 65536 + cur * 32768;
        char* An = sm + (cur ^ 1) * 32768;
        char* Bn = sm + 65536 + (cur ^ 1) * 32768;
        const int k1 = (t + 1) << 7;
        const int k2 = (t + 2) << 7;

        // ---- P0: stage A0+A1(t+1)->next-A (after B2(t-1): WAR-safe);
        //          wait aF0/bF01 (12 oldest); MFMA q(0,0) ----
        if (t + 1 < NT) {
            STAGE(An,         pA + k1);
            STAGE(An + 16384, pA + hK + k1);
        }
        LGKM(4);                       // aF0,bF01 ready; bF23 still in flight
        __builtin_amdgcn_s_setprio(1);
        MFMA8(aF0, bF01, 0, 0);
        __builtin_amdgcn_s_setprio(0);

        // ---- P1: issue aF1; wait bF23; MFMA; vmcnt(0); BARRIER B1 ----
        RD_A(aF1, Ab, 4);
        LGKM(8);                       // bF23 ready (aF1 in flight)
        __builtin_amdgcn_s_setprio(1);
        MFMA8(aF0, bF23, 0, 2);
        __builtin_amdgcn_s_setprio(0);
        asm volatile("s_waitcnt vmcnt(0)" ::: "memory");
        __builtin_amdgcn_s_barrier();  // B1: publish ALL of tile t+1

        // ---- P2: stage B0(t+2)->cur-B; wait aF1; MFMA (old bF01);
        //          then early-read t+1 mh0/n01 ----
        if (t + 2 < NT) STAGE(Bb, pB + k2);
        LGKM(0);                       // aF1 ready
        __builtin_amdgcn_s_setprio(1);
        MFMA8(aF1, bF01, 4, 0);
        __builtin_amdgcn_s_setprio(0);
        if (t + 1 < NT) {
            RD_A(aF0, An, 0);          // t+1 mh0 (published at B1)
            RD_B(bF01, Bn, 0);         // t+1 n0,n1 (published at B1)
        }

        // ---- P3: stage B1(t+2); MFMA q(1,1) with OLD bF23 FIRST;
        //          then early-read bF23(t+1); BARRIER B2 (no vmcnt) ----
        if (t + 2 < NT) STAGE(Bb + 16384, pB + hK + k2);
        __builtin_amdgcn_s_setprio(1);
        MFMA8(aF1, bF23, 4, 2);        // consumes tile t's bF23
        __builtin_amdgcn_s_setprio(0);
        if (t + 1 < NT) RD_B(bF23, Bn, 2);  // t+1 n2,n3 (published at B1)
        __builtin_amdgcn_s_barrier();  // B2: exec-sync before next P0 A-staging
    }

    // ---- epilogue: out = acc * (rs[row]*scale[col]) + bias[col] ----
    // C/D 16x16 layout (shape-determined, m121-128): col=l15, row=l4*4+j
#pragma unroll
    for (int n = 0; n < 4; ++n) {
        const int col = n0 + wc * 64 + n * 16 + l15;
        const float sc = scale[col];
        const float bs = bias[col];
#pragma unroll
        for (int m = 0; m < 8; ++m) {
            const int row0 = m0 + wr * 128 + m * 16 + l4 * 4;
#pragma unroll
            for (int j = 0; j < 4; ++j)
                C[(size_t)(row0 + j) * N + col] =
                    (float)acc[m][n][j] * (rs[row0 + j] * sc) + bs;
        }
    }
#undef STAGE
#undef RD_A
#undef RD_B
#undef MFMA8
#undef LGKM
}

// ---------------- fallback (shape mismatch): 2-phase bf16, on-the-fly ----
__global__ __launch_bounds__(256) void qgemm_fb_kernel(
    const float* __restrict__ Af, const int* __restrict__ Bi,
    const float* __restrict__ scale, const float* __restrict__ bias,
    float* __restrict__ C, int M, int N, int K) {
    constexpr int BK = 64;
    __shared__ unsigned short lA[128 * BK];
    __shared__ unsigned short lB[128 * BK];
    const int t = threadIdx.x, lane = t & 63, w = t >> 6;
    const int wr = w >> 1, wc = w & 1;
    const int m0 = blockIdx.y * 128, n0 = blockIdx.x * 128;
    const int l15 = lane & 15, l4 = lane >> 4;
    f32x4 acc[4][4];
#pragma unroll
    for (int m = 0; m < 4; ++m)
#pragma unroll
        for (int n = 0; n < 4; ++n) acc[m][n] = (f32x4){0.f, 0.f, 0.f, 0.f};
    for (int k0 = 0; k0 < K; k0 += BK) {
        __syncthreads();
#pragma unroll
        for (int i = 0; i < 4; ++i) {
            const int off = i * 4096 + w * 1024 + lane * 16;
            const int row = off >> 7;
            const int col = (off & 127) >> 1;
            const float* pa = Af + (size_t)(m0 + row) * K + k0 + col;
            float4 a0 = *(const float4*)pa;
            float4 a1 = *(const float4*)(pa + 4);
            ushort8 va;
            va[0] = f32_to_bf16(a0.x); va[1] = f32_to_bf16(a0.y);
            va[2] = f32_to_bf16(a0.z); va[3] = f32_to_bf16(a0.w);
            va[4] = f32_to_bf16(a1.x); va[5] = f32_to_bf16(a1.y);
            va[6] = f32_to_bf16(a1.z); va[7] = f32_to_bf16(a1.w);
            *(ushort8*)((char*)lA + off) = va;
            const int* pb = Bi + (size_t)(n0 + row) * K + k0 + col;
            int4 b0 = *(const int4*)pb;
            int4 b1 = *(const int4*)(pb + 4);
            ushort8 vb;
            vb[0] = f32_to_bf16((float)b0.x); vb[1] = f32_to_bf16((float)b0.y);
            vb[2] = f32_to_bf16((float)b0.z); vb[3] = f32_to_bf16((float)b0.w);
            vb[4] = f32_to_bf16((float)b1.x); vb[5] = f32_to_bf16((float)b1.y);
            vb[6] = f32_to_bf16((float)b1.z); vb[7] = f32_to_bf16((float)b1.w);
            *(ushort8*)((char*)lB + off) = vb;
        }
        __syncthreads();
#pragma unroll
        for (int kk = 0; kk < BK; kk += 32) {
            bf16x8 af[4], bfr[4];
#pragma unroll
            for (int m = 0; m < 4; ++m)
                af[m] = *(const bf16x8*)&lA[(wr * 64 + m * 16 + l15) * BK + kk + l4 * 8];
#pragma unroll
            for (int n = 0; n < 4; ++n)
                bfr[n] = *(const bf16x8*)&lB[(wc * 64 + n * 16 + l15) * BK + kk + l4 * 8];
#pragma unroll
            for (int m = 0; m < 4; ++m)
#pragma unroll
                for (int n = 0; n < 4; ++n)
                    acc[m][n] = __builtin_amdgcn_mfma_f32_16x16x32_bf16(
                        af[m], bfr[n], acc[m][n], 0, 0, 0);
        }
    }
#pragma unroll
    for (int n = 0; n < 4; ++n) {
        const int col = n0 + wc * 64 + n * 16 + l15;
        const float sc = scale[col], bs = bias[col];
#pragma unroll
        for (int m = 0; m < 4; ++m) {
            const int row0 = m0 + wr * 64 + m * 16 + l4 * 4;
#pragma unroll
            for (int j = 0; j < 4; ++j)
                C[(size_t)(row0 + j) * N + col] = fmaf(acc[m][n][j], sc, bs);
        }
    }
}

extern "C" void kernel_launch(void* const* d_in, const int* in_sizes, int n_in,
                              void* d_out, int out_size, void* d_ws, size_t ws_size,
                              hipStream_t stream) {
    const float* x     = (const float*)d_in[0];
    const int*   q     = (const int*)d_in[1];
    const float* scale = (const float*)d_in[2];
    const float* bias  = (const float*)d_in[3];
    float*       out   = (float*)d_out;

    const int K = in_sizes[2];
    const int N = in_sizes[1] / K;
    const int M = in_sizes[0] / K;

    const size_t xq_b = (size_t)M * K;
    const size_t qb_b = (size_t)N * K;
    const size_t need = xq_b + qb_b + (size_t)M * 4;
    const int nwg = (M / 256) * (N / 256);

    if (ws_size >= need && (M % 256) == 0 && (N % 256) == 0 &&
        (K % 128) == 0 && K >= 256 && (nwg % 8) == 0) {
        char*  xq = (char*)d_ws;
        char*  qb = xq + xq_b;
        float* rs = (float*)(qb + qb_b);
        quantx_kernel<<<M, 256, 0, stream>>>(x, xq, rs, K);
        convq_kernel<<<2048, 256, 0, stream>>>(q, qb, (long)(qb_b / 16));
        qgemm_i8_kernel<<<nwg, 512, 131072, stream>>>(xq, qb, rs, scale, bias,
                                                      out, M, N, K);
    } else {
        dim3 grid(N / 128, M / 128);
        qgemm_fb_kernel<<<grid, 256, 0, stream>>>(x, q, scale, bias, out, M, N, K);
    }
}